// Round 12
// baseline (35.540 us; speedup 1.0000x reference)
//
#include <hip/hip_runtime.h>
#include <math.h>

#define HD 768
#define NL 3
#define BB 64
#define SS 512
#define NEG (-1e30f)

typedef float nt_float4 __attribute__((ext_vector_type(4)));

__device__ __forceinline__ float lse3(float x, float y, float z) {
    float m = fmaxf(fmaxf(x, y), z);
    return m + __logf(__expf(x - m) + __expf(y - m) + __expf(z - m));
}

// 16 lanes per token, 4 tokens per wave. Lane q (=lane&15) loads float4
// chunks q+16i (i=0..11) of the 768-float row via NONTEMPORAL loads (hidden
// is a 100 MB read-once stream; nt skips cache allocation), 4-level shfl
// reduce within the 16-lane group. em layout [B,S,4]: one float4 per token.
__global__ __launch_bounds__(256) void emis_kernel(
    const float* __restrict__ hidden, const float* __restrict__ W,
    const float* __restrict__ bias, float* __restrict__ em,
    float* __restrict__ out) {
    if (blockIdx.x == 0 && threadIdx.x == 0) out[0] = 0.f;  // init for atomics
    int gid  = blockIdx.x * blockDim.x + threadIdx.x;
    int wave = gid >> 6;
    int l    = threadIdx.x & 63;
    int q    = l & 15;            // lane within 16-lane token group
    int sub  = l >> 4;            // token within wave
    int tok  = wave * 4 + sub;    // 8192 waves * 4 = 32768 tokens

    const nt_float4* h4 = (const nt_float4*)(hidden + (size_t)tok * HD);
    float a0 = 0.f, a1 = 0.f, a2 = 0.f;
#pragma unroll
    for (int i = 0; i < 12; ++i) {
        int k4 = q + 16 * i;
        nt_float4 v = __builtin_nontemporal_load(h4 + k4);
        int k = k4 * 4;
        a0 = fmaf(v.x, W[(k + 0) * 3 + 0], a0);
        a1 = fmaf(v.x, W[(k + 0) * 3 + 1], a1);
        a2 = fmaf(v.x, W[(k + 0) * 3 + 2], a2);
        a0 = fmaf(v.y, W[(k + 1) * 3 + 0], a0);
        a1 = fmaf(v.y, W[(k + 1) * 3 + 1], a1);
        a2 = fmaf(v.y, W[(k + 1) * 3 + 2], a2);
        a0 = fmaf(v.z, W[(k + 2) * 3 + 0], a0);
        a1 = fmaf(v.z, W[(k + 2) * 3 + 1], a1);
        a2 = fmaf(v.z, W[(k + 2) * 3 + 2], a2);
        a0 = fmaf(v.w, W[(k + 3) * 3 + 0], a0);
        a1 = fmaf(v.w, W[(k + 3) * 3 + 1], a1);
        a2 = fmaf(v.w, W[(k + 3) * 3 + 2], a2);
    }
#pragma unroll
    for (int off = 8; off; off >>= 1) {      // reduce within 16-lane group
        a0 += __shfl_down(a0, off);
        a1 += __shfl_down(a1, off);
        a2 += __shfl_down(a2, off);
    }
    if (q == 0) {
        int b = tok >> 9;
        int s = tok & (SS - 1);
        float4 o = {a0 + bias[0], a1 + bias[1], a2 + bias[2], 0.f};
        ((float4*)em)[(size_t)b * SS + s] = o;
    }
}

// 64 blocks (one per batch) x 256 threads (4 waves). Wave w covers steps
// [w*128, (w+1)*128); lane owns 2 steps (one aligned float4 each from the
// stride-4 em). Register-resident, branchless. Per-wave 6-level shfl tree ->
// 4 partials in LDS -> thread 0 chains them, finalizes, atomicAdds the mean.
__global__ __launch_bounds__(256) void crf_fused_kernel(
    const float* __restrict__ em,          // [B,S,4]
    const int* __restrict__ mask,          // [B,S]
    const int* __restrict__ labels,        // [B,S]
    const float* __restrict__ startT, const float* __restrict__ endT,
    const float* __restrict__ trans, float* __restrict__ out) {
    int b = blockIdx.x;
    int w = threadIdx.x >> 6;
    int l = threadIdx.x & 63;
    int s0 = w * 128 + l * 2;

    float T00 = trans[0], T01 = trans[1], T02 = trans[2];
    float T10 = trans[3], T11 = trans[4], T12 = trans[5];
    float T20 = trans[6], T21 = trans[7], T22 = trans[8];

    const float* emb = em + (size_t)b * SS * 4;
    const int*   tg  = labels + b * SS;
    const int*   mk  = mask + b * SS;

    const float4* ep4 = (const float4*)emb;
    float4 Ea = ep4[s0], Eb = ep4[s0 + 1];
    int2 tt = *(const int2*)(tg + s0);
    int2 mm = *(const int2*)(mk + s0);
    int pv = (s0 > 0) ? tg[s0 - 1] : 0;
    int prev = pv < 0 ? 0 : pv;

    float P00, P01, P02, P10, P11, P12, P20, P21, P22;
    float gold = 0.f;
    int last_s = -1, last_t = 0;

#define GOLD(kk, ee0, ee1, ee2, tv, mv, ACT)                                   \
    int t = (tv) < 0 ? 0 : (tv);                                               \
    bool act = (ACT) && ((mv) != 0);                                           \
    {                                                                          \
        float ev = (t == 0) ? (ee0) : ((t == 1) ? (ee1) : (ee2));              \
        float r0 = (t == 0) ? T00 : ((t == 1) ? T01 : T02);                    \
        float r1 = (t == 0) ? T10 : ((t == 1) ? T11 : T12);                    \
        float r2 = (t == 0) ? T20 : ((t == 1) ? T21 : T22);                    \
        float tpt = (prev == 0) ? r0 : ((prev == 1) ? r1 : r2);                \
        gold += act ? (ev + tpt) : 0.f;                                        \
        last_t = act ? t : last_t;                                             \
        last_s = act ? (s0 + (kk)) : last_s;                                   \
        prev = t;                                                              \
    }

#define STEP0(ee0, ee1, ee2, tv, mv) {                                         \
    GOLD(0, ee0, ee1, ee2, tv, mv, (s0 > 0))                                   \
    P00 = act ? (T00 + (ee0)) : 0.f;                                           \
    P01 = act ? (T01 + (ee1)) : NEG;                                           \
    P02 = act ? (T02 + (ee2)) : NEG;                                           \
    P10 = act ? (T10 + (ee0)) : NEG;                                           \
    P11 = act ? (T11 + (ee1)) : 0.f;                                           \
    P12 = act ? (T12 + (ee2)) : NEG;                                           \
    P20 = act ? (T20 + (ee0)) : NEG;                                           \
    P21 = act ? (T21 + (ee1)) : NEG;                                           \
    P22 = act ? (T22 + (ee2)) : 0.f;                                           \
}

#define STEPK(kk, ee0, ee1, ee2, tv, mv) {                                     \
    GOLD(kk, ee0, ee1, ee2, tv, mv, true)                                      \
    float n00 = lse3(P00 + T00, P01 + T10, P02 + T20) + (ee0);                 \
    float n01 = lse3(P00 + T01, P01 + T11, P02 + T21) + (ee1);                 \
    float n02 = lse3(P00 + T02, P01 + T12, P02 + T22) + (ee2);                 \
    float n10 = lse3(P10 + T00, P11 + T10, P12 + T20) + (ee0);                 \
    float n11 = lse3(P10 + T01, P11 + T11, P12 + T21) + (ee1);                 \
    float n12 = lse3(P10 + T02, P11 + T12, P12 + T22) + (ee2);                 \
    float n20 = lse3(P20 + T00, P21 + T10, P22 + T20) + (ee0);                 \
    float n21 = lse3(P20 + T01, P21 + T11, P22 + T21) + (ee1);                 \
    float n22 = lse3(P20 + T02, P21 + T12, P22 + T22) + (ee2);                 \
    P00 = act ? n00 : P00; P01 = act ? n01 : P01; P02 = act ? n02 : P02;       \
    P10 = act ? n10 : P10; P11 = act ? n11 : P11; P12 = act ? n12 : P12;       \
    P20 = act ? n20 : P20; P21 = act ? n21 : P21; P22 = act ? n22 : P22;       \
}

    STEP0(    Ea.x, Ea.y, Ea.z, tt.x, mm.x)
    STEPK(1,  Eb.x, Eb.y, Eb.z, tt.y, mm.y)

    // in-wave tree: offsets MUST increase (non-commutative product).
#pragma unroll
    for (int off = 1; off < 64; off <<= 1) {
        float B00 = __shfl_down(P00, off), B01 = __shfl_down(P01, off);
        float B02 = __shfl_down(P02, off), B10 = __shfl_down(P10, off);
        float B11 = __shfl_down(P11, off), B12 = __shfl_down(P12, off);
        float B20 = __shfl_down(P20, off), B21 = __shfl_down(P21, off);
        float B22 = __shfl_down(P22, off);
        float n00 = lse3(P00 + B00, P01 + B10, P02 + B20);
        float n01 = lse3(P00 + B01, P01 + B11, P02 + B21);
        float n02 = lse3(P00 + B02, P01 + B12, P02 + B22);
        float n10 = lse3(P10 + B00, P11 + B10, P12 + B20);
        float n11 = lse3(P10 + B01, P11 + B11, P12 + B21);
        float n12 = lse3(P10 + B02, P11 + B12, P12 + B22);
        float n20 = lse3(P20 + B00, P21 + B10, P22 + B20);
        float n21 = lse3(P20 + B01, P21 + B11, P22 + B21);
        float n22 = lse3(P20 + B02, P21 + B12, P22 + B22);
        P00 = n00; P01 = n01; P02 = n02;
        P10 = n10; P11 = n11; P12 = n12;
        P20 = n20; P21 = n21; P22 = n22;

        gold += __shfl_down(gold, off);
        int os = __shfl_down(last_s, off);
        int ot = __shfl_down(last_t, off);
        if (os > last_s) { last_s = os; last_t = ot; }
    }

    __shared__ float lds[4][12];
    if (l == 0) {
        lds[w][0] = P00; lds[w][1] = P01; lds[w][2] = P02;
        lds[w][3] = P10; lds[w][4] = P11; lds[w][5] = P12;
        lds[w][6] = P20; lds[w][7] = P21; lds[w][8] = P22;
        lds[w][9] = gold;
        lds[w][10] = __int_as_float(last_s);
        lds[w][11] = __int_as_float(last_t);
    }
    __syncthreads();

    if (threadIdx.x == 0) {
        float R00 = lds[0][0], R01 = lds[0][1], R02 = lds[0][2];
        float R10 = lds[0][3], R11 = lds[0][4], R12 = lds[0][5];
        float R20 = lds[0][6], R21 = lds[0][7], R22 = lds[0][8];
        float g  = lds[0][9];
        int ls = __float_as_int(lds[0][10]), lt = __float_as_int(lds[0][11]);
#pragma unroll
        for (int c = 1; c < 4; ++c) {
            float B00 = lds[c][0], B01 = lds[c][1], B02 = lds[c][2];
            float B10 = lds[c][3], B11 = lds[c][4], B12 = lds[c][5];
            float B20 = lds[c][6], B21 = lds[c][7], B22 = lds[c][8];
            float n00 = lse3(R00 + B00, R01 + B10, R02 + B20);
            float n01 = lse3(R00 + B01, R01 + B11, R02 + B21);
            float n02 = lse3(R00 + B02, R01 + B12, R02 + B22);
            float n10 = lse3(R10 + B00, R11 + B10, R12 + B20);
            float n11 = lse3(R10 + B01, R11 + B11, R12 + B21);
            float n12 = lse3(R10 + B02, R11 + B12, R12 + B22);
            float n20 = lse3(R20 + B00, R21 + B10, R22 + B20);
            float n21 = lse3(R20 + B01, R21 + B11, R22 + B21);
            float n22 = lse3(R20 + B02, R21 + B12, R22 + B22);
            R00 = n00; R01 = n01; R02 = n02;
            R10 = n10; R11 = n11; R12 = n12;
            R20 = n20; R21 = n21; R22 = n22;
            g += lds[c][9];
            int os = __float_as_int(lds[c][10]);
            int ot = __float_as_int(lds[c][11]);
            if (os > ls) { ls = os; lt = ot; }
        }

        float e00 = emb[0], e01 = emb[1], e02 = emb[2];
        int t0 = tg[0]; t0 = t0 < 0 ? 0 : t0;
        float st0 = startT[0], st1 = startT[1], st2 = startT[2];
        float en0 = endT[0],   en1 = endT[1],   en2 = endT[2];

        float al0 = st0 + e00, al1 = st1 + e01, al2 = st2 + e02;
        float f0 = lse3(al0 + R00, al1 + R10, al2 + R20);
        float f1 = lse3(al0 + R01, al1 + R11, al2 + R21);
        float f2 = lse3(al0 + R02, al1 + R12, al2 + R22);
        float logZ = lse3(f0 + en0, f1 + en1, f2 + en2);
        float sc0 = ((t0 == 0) ? st0 : ((t0 == 1) ? st1 : st2)) +
                    ((t0 == 0) ? e00 : ((t0 == 1) ? e01 : e02));
        if (ls < 0) lt = t0;
        float endv = (lt == 0) ? en0 : ((lt == 1) ? en1 : en2);
        float contrib = logZ - (sc0 + g + endv);
        atomicAdd(out, contrib * (1.0f / BB));
    }
}

extern "C" void kernel_launch(void* const* d_in, const int* in_sizes, int n_in,
                              void* d_out, int out_size, void* d_ws, size_t ws_size,
                              hipStream_t stream) {
    const float* hidden = (const float*)d_in[0];
    const float* W      = (const float*)d_in[1];
    const float* bias   = (const float*)d_in[2];
    const float* startT = (const float*)d_in[3];
    const float* endT   = (const float*)d_in[4];
    const float* trans  = (const float*)d_in[5];
    const int*   mask   = (const int*)d_in[6];
    const int*   labels = (const int*)d_in[7];
    float* out = (float*)d_out;

    float* em = (float*)d_ws;                   // B*S*4 floats = 512 KiB

    // 8192 waves * 4 tokens/wave = 32768 tokens; 4 waves per block
    emis_kernel<<<2048, 256, 0, stream>>>(hidden, W, bias, em, out);
    crf_fused_kernel<<<BB, 256, 0, stream>>>(em, mask, labels, startT, endT,
                                             trans, out);
}

// Round 13
// 29.929 us; speedup vs baseline: 1.1875x; 1.1875x over previous
//
#include <hip/hip_runtime.h>
#include <math.h>

#define HD 768
#define NL 3
#define BB 64
#define SS 512
#define NEG (-1e30f)

__device__ __forceinline__ float lse3(float x, float y, float z) {
    float m = fmaxf(fmaxf(x, y), z);
    return m + __logf(__expf(x - m) + __expf(y - m) + __expf(z - m));
}

// One wave (64 lanes) per token. Lane l loads float4 chunks l, l+64, l+128 of
// the 768-float hidden row, accumulates 3 dot products, wave-reduces.
// Output layout: em[(b*S + s)*3 + j]  ([B,S,3]).
__global__ __launch_bounds__(256) void emis_kernel(
    const float* __restrict__ hidden, const float* __restrict__ W,
    const float* __restrict__ bias, float* __restrict__ em) {
    int gid  = blockIdx.x * blockDim.x + threadIdx.x;
    int wave = gid >> 6;
    int lane = threadIdx.x & 63;
    int BS = BB * SS;
    if (wave >= BS) return;
    const float4* h4 = (const float4*)(hidden + (size_t)wave * HD);
    float a0 = 0.f, a1 = 0.f, a2 = 0.f;
#pragma unroll
    for (int i = 0; i < 3; ++i) {
        int k4 = lane + 64 * i;          // float4 index within the row
        float4 v = h4[k4];
        int k = k4 * 4;
        a0 = fmaf(v.x, W[(k + 0) * 3 + 0], a0);
        a1 = fmaf(v.x, W[(k + 0) * 3 + 1], a1);
        a2 = fmaf(v.x, W[(k + 0) * 3 + 2], a2);
        a0 = fmaf(v.y, W[(k + 1) * 3 + 0], a0);
        a1 = fmaf(v.y, W[(k + 1) * 3 + 1], a1);
        a2 = fmaf(v.y, W[(k + 1) * 3 + 2], a2);
        a0 = fmaf(v.z, W[(k + 2) * 3 + 0], a0);
        a1 = fmaf(v.z, W[(k + 2) * 3 + 1], a1);
        a2 = fmaf(v.z, W[(k + 2) * 3 + 2], a2);
        a0 = fmaf(v.w, W[(k + 3) * 3 + 0], a0);
        a1 = fmaf(v.w, W[(k + 3) * 3 + 1], a1);
        a2 = fmaf(v.w, W[(k + 3) * 3 + 2], a2);
    }
#pragma unroll
    for (int off = 32; off; off >>= 1) {
        a0 += __shfl_down(a0, off);
        a1 += __shfl_down(a1, off);
        a2 += __shfl_down(a2, off);
    }
    if (lane == 0) {
        int b = wave >> 9;           // wave / SS
        int s = wave & (SS - 1);     // wave % SS
        float* o = em + ((size_t)b * SS + s) * NL;
        o[0] = a0 + bias[0];
        o[1] = a1 + bias[1];
        o[2] = a2 + bias[2];
    }
}

// 256 blocks: block = (b = idx&63, c = idx>>6). Chunk c covers steps
// [c*128, (c+1)*128); lane l owns 2 steps s0 = c*128 + 2l. Register-resident,
// branchless. Per-lane: STEP0 + STEPK, then 6-level shfl tree over the wave.
// Lane 0 stores the chunk partial: 9 P + gold + last_s + last_t (3 float4).
__global__ __launch_bounds__(64) void crf_part_kernel(
    const float* __restrict__ em,          // [B,S,3]
    const int* __restrict__ mask,          // [B,S]
    const int* __restrict__ labels,        // [B,S]
    const float* __restrict__ trans, float* __restrict__ part) {
    int idx = blockIdx.x;
    int b = idx & 63;
    int c = idx >> 6;
    int l = threadIdx.x;
    int s0 = c * 128 + l * 2;

    float T00 = trans[0], T01 = trans[1], T02 = trans[2];
    float T10 = trans[3], T11 = trans[4], T12 = trans[5];
    float T20 = trans[6], T21 = trans[7], T22 = trans[8];

    const float* emb = em + (size_t)b * SS * NL;
    const int*   tg  = labels + b * SS;
    const int*   mk  = mask + b * SS;

    const float2* e2 = (const float2*)(emb + (size_t)s0 * NL);  // 24B-aligned
    float2 v01 = e2[0], v23 = e2[1], v45 = e2[2];
    int2 tt = *(const int2*)(tg + s0);
    int2 mm = *(const int2*)(mk + s0);
    int pv = (s0 > 0) ? tg[s0 - 1] : 0;
    int prev = pv < 0 ? 0 : pv;

    float P00, P01, P02, P10, P11, P12, P20, P21, P22;
    float gold = 0.f;
    int last_s = -1, last_t = 0;

#define GOLD(kk, ee0, ee1, ee2, tv, mv, ACT)                                   \
    int t = (tv) < 0 ? 0 : (tv);                                               \
    bool act = (ACT) && ((mv) != 0);                                           \
    {                                                                          \
        float ev = (t == 0) ? (ee0) : ((t == 1) ? (ee1) : (ee2));              \
        float r0 = (t == 0) ? T00 : ((t == 1) ? T01 : T02);                    \
        float r1 = (t == 0) ? T10 : ((t == 1) ? T11 : T12);                    \
        float r2 = (t == 0) ? T20 : ((t == 1) ? T21 : T22);                    \
        float tpt = (prev == 0) ? r0 : ((prev == 1) ? r1 : r2);                \
        gold += act ? (ev + tpt) : 0.f;                                        \
        last_t = act ? t : last_t;                                             \
        last_s = act ? (s0 + (kk)) : last_s;                                   \
        prev = t;                                                              \
    }

#define STEP0(ee0, ee1, ee2, tv, mv) {                                         \
    GOLD(0, ee0, ee1, ee2, tv, mv, (s0 > 0))                                   \
    P00 = act ? (T00 + (ee0)) : 0.f;                                           \
    P01 = act ? (T01 + (ee1)) : NEG;                                           \
    P02 = act ? (T02 + (ee2)) : NEG;                                           \
    P10 = act ? (T10 + (ee0)) : NEG;                                           \
    P11 = act ? (T11 + (ee1)) : 0.f;                                           \
    P12 = act ? (T12 + (ee2)) : NEG;                                           \
    P20 = act ? (T20 + (ee0)) : NEG;                                           \
    P21 = act ? (T21 + (ee1)) : NEG;                                           \
    P22 = act ? (T22 + (ee2)) : 0.f;                                           \
}

#define STEPK(kk, ee0, ee1, ee2, tv, mv) {                                     \
    GOLD(kk, ee0, ee1, ee2, tv, mv, true)                                      \
    float n00 = lse3(P00 + T00, P01 + T10, P02 + T20) + (ee0);                 \
    float n01 = lse3(P00 + T01, P01 + T11, P02 + T21) + (ee1);                 \
    float n02 = lse3(P00 + T02, P01 + T12, P02 + T22) + (ee2);                 \
    float n10 = lse3(P10 + T00, P11 + T10, P12 + T20) + (ee0);                 \
    float n11 = lse3(P10 + T01, P11 + T11, P12 + T21) + (ee1);                 \
    float n12 = lse3(P10 + T02, P11 + T12, P12 + T22) + (ee2);                 \
    float n20 = lse3(P20 + T00, P21 + T10, P22 + T20) + (ee0);                 \
    float n21 = lse3(P20 + T01, P21 + T11, P22 + T21) + (ee1);                 \
    float n22 = lse3(P20 + T02, P21 + T12, P22 + T22) + (ee2);                 \
    P00 = act ? n00 : P00; P01 = act ? n01 : P01; P02 = act ? n02 : P02;       \
    P10 = act ? n10 : P10; P11 = act ? n11 : P11; P12 = act ? n12 : P12;       \
    P20 = act ? n20 : P20; P21 = act ? n21 : P21; P22 = act ? n22 : P22;       \
}

    STEP0(    v01.x, v01.y, v23.x, tt.x, mm.x)
    STEPK(1,  v23.y, v45.x, v45.y, tt.y, mm.y)

    // tree combine: offsets MUST increase (non-commutative product).
#pragma unroll
    for (int off = 1; off < 64; off <<= 1) {
        float B00 = __shfl_down(P00, off), B01 = __shfl_down(P01, off);
        float B02 = __shfl_down(P02, off), B10 = __shfl_down(P10, off);
        float B11 = __shfl_down(P11, off), B12 = __shfl_down(P12, off);
        float B20 = __shfl_down(P20, off), B21 = __shfl_down(P21, off);
        float B22 = __shfl_down(P22, off);
        float n00 = lse3(P00 + B00, P01 + B10, P02 + B20);
        float n01 = lse3(P00 + B01, P01 + B11, P02 + B21);
        float n02 = lse3(P00 + B02, P01 + B12, P02 + B22);
        float n10 = lse3(P10 + B00, P11 + B10, P12 + B20);
        float n11 = lse3(P10 + B01, P11 + B11, P12 + B21);
        float n12 = lse3(P10 + B02, P11 + B12, P12 + B22);
        float n20 = lse3(P20 + B00, P21 + B10, P22 + B20);
        float n21 = lse3(P20 + B01, P21 + B11, P22 + B21);
        float n22 = lse3(P20 + B02, P21 + B12, P22 + B22);
        P00 = n00; P01 = n01; P02 = n02;
        P10 = n10; P11 = n11; P12 = n12;
        P20 = n20; P21 = n21; P22 = n22;

        gold += __shfl_down(gold, off);
        int os = __shfl_down(last_s, off);
        int ot = __shfl_down(last_t, off);
        if (os > last_s) { last_s = os; last_t = ot; }
    }

    if (l == 0) {
        float4* dst = (float4*)part + ((size_t)c * BB + b) * 3;
        float4 q0 = {P00, P01, P02, P10};
        float4 q1 = {P11, P12, P20, P21};
        float4 q2 = {P22, gold, __int_as_float(last_s), __int_as_float(last_t)};
        dst[0] = q0; dst[1] = q1; dst[2] = q2;
    }
}

struct M3 { float a00,a01,a02,a10,a11,a12,a20,a21,a22; };

__device__ __forceinline__ M3 otimes(const M3& P, const M3& B) {
    M3 N;
    N.a00 = lse3(P.a00 + B.a00, P.a01 + B.a10, P.a02 + B.a20);
    N.a01 = lse3(P.a00 + B.a01, P.a01 + B.a11, P.a02 + B.a21);
    N.a02 = lse3(P.a00 + B.a02, P.a01 + B.a12, P.a02 + B.a22);
    N.a10 = lse3(P.a10 + B.a00, P.a11 + B.a10, P.a12 + B.a20);
    N.a11 = lse3(P.a10 + B.a01, P.a11 + B.a11, P.a12 + B.a21);
    N.a12 = lse3(P.a10 + B.a02, P.a11 + B.a12, P.a12 + B.a22);
    N.a20 = lse3(P.a20 + B.a00, P.a21 + B.a10, P.a22 + B.a20);
    N.a21 = lse3(P.a20 + B.a01, P.a21 + B.a11, P.a22 + B.a21);
    N.a22 = lse3(P.a20 + B.a02, P.a21 + B.a12, P.a22 + B.a22);
    return N;
}

// One wave: thread b chains the 4 chunk partials (left-to-right), finalizes
// logZ/score for batch b, then tree-sums the mean. Deterministic.
__global__ __launch_bounds__(64) void crf_combine_kernel(
    const float* __restrict__ part, const float* __restrict__ em,
    const int* __restrict__ labels,
    const float* __restrict__ startT, const float* __restrict__ endT,
    float* __restrict__ out) {
    int b = threadIdx.x;
    const float4* pp = (const float4*)part;

    float4 a0 = pp[(0 * BB + b) * 3 + 0], a1 = pp[(0 * BB + b) * 3 + 1],
           a2 = pp[(0 * BB + b) * 3 + 2];
    float4 b0 = pp[(1 * BB + b) * 3 + 0], b1 = pp[(1 * BB + b) * 3 + 1],
           b2 = pp[(1 * BB + b) * 3 + 2];
    float4 c0 = pp[(2 * BB + b) * 3 + 0], c1 = pp[(2 * BB + b) * 3 + 1],
           c2 = pp[(2 * BB + b) * 3 + 2];
    float4 d0 = pp[(3 * BB + b) * 3 + 0], d1 = pp[(3 * BB + b) * 3 + 1],
           d2 = pp[(3 * BB + b) * 3 + 2];

    M3 R  = {a0.x, a0.y, a0.z, a0.w, a1.x, a1.y, a1.z, a1.w, a2.x};
    M3 M1 = {b0.x, b0.y, b0.z, b0.w, b1.x, b1.y, b1.z, b1.w, b2.x};
    M3 M2 = {c0.x, c0.y, c0.z, c0.w, c1.x, c1.y, c1.z, c1.w, c2.x};
    M3 M3v = {d0.x, d0.y, d0.z, d0.w, d1.x, d1.y, d1.z, d1.w, d2.x};
    R = otimes(R, M1);
    R = otimes(R, M2);
    R = otimes(R, M3v);

    float gold = a2.y + b2.y + c2.y + d2.y;
    int last_s = __float_as_int(a2.z), last_t = __float_as_int(a2.w);
    int s1 = __float_as_int(b2.z), t1 = __float_as_int(b2.w);
    int s2 = __float_as_int(c2.z), t2 = __float_as_int(c2.w);
    int s3 = __float_as_int(d2.z), t3 = __float_as_int(d2.w);
    if (s1 > last_s) { last_s = s1; last_t = t1; }
    if (s2 > last_s) { last_s = s2; last_t = t2; }
    if (s3 > last_s) { last_s = s3; last_t = t3; }

    const float* emb = em + (size_t)b * SS * NL;
    float e00 = emb[0], e01 = emb[1], e02 = emb[2];
    int t0 = labels[b * SS]; t0 = t0 < 0 ? 0 : t0;
    float st0 = startT[0], st1 = startT[1], st2 = startT[2];
    float en0 = endT[0],   en1 = endT[1],   en2 = endT[2];

    float al0 = st0 + e00, al1 = st1 + e01, al2 = st2 + e02;
    float f0 = lse3(al0 + R.a00, al1 + R.a10, al2 + R.a20);
    float f1 = lse3(al0 + R.a01, al1 + R.a11, al2 + R.a21);
    float f2 = lse3(al0 + R.a02, al1 + R.a12, al2 + R.a22);
    float logZ = lse3(f0 + en0, f1 + en1, f2 + en2);
    float sc0 = ((t0 == 0) ? st0 : ((t0 == 1) ? st1 : st2)) +
                ((t0 == 0) ? e00 : ((t0 == 1) ? e01 : e02));
    if (last_s < 0) last_t = t0;
    float endv = (last_t == 0) ? en0 : ((last_t == 1) ? en1 : en2);
    float contrib = logZ - (sc0 + gold + endv);

#pragma unroll
    for (int off = 32; off; off >>= 1) contrib += __shfl_down(contrib, off);
    if (b == 0) out[0] = contrib * (1.0f / BB);
}

extern "C" void kernel_launch(void* const* d_in, const int* in_sizes, int n_in,
                              void* d_out, int out_size, void* d_ws, size_t ws_size,
                              hipStream_t stream) {
    const float* hidden = (const float*)d_in[0];
    const float* W      = (const float*)d_in[1];
    const float* bias   = (const float*)d_in[2];
    const float* startT = (const float*)d_in[3];
    const float* endT   = (const float*)d_in[4];
    const float* trans  = (const float*)d_in[5];
    const int*   mask   = (const int*)d_in[6];
    const int*   labels = (const int*)d_in[7];
    float* out = (float*)d_out;

    float* em   = (float*)d_ws;                 // B*S*3 floats = 384 KiB
    float* part = em + (size_t)BB * SS * NL;    // 4*64*12 floats = 12 KiB

    int BS = BB * SS;                           // 32768 tokens, one wave each
    int blocks = BS / 4;                        // 4 waves per 256-thread block
    emis_kernel<<<blocks, 256, 0, stream>>>(hidden, W, bias, em);
    crf_part_kernel<<<4 * BB, 64, 0, stream>>>(em, mask, labels, trans, part);
    crf_combine_kernel<<<1, 64, 0, stream>>>(part, em, labels, startT, endT, out);
}